// Round 6
// baseline (22.262 us; speedup 1.0000x reference)
//
#include <hip/hip_runtime.h>

#define N_ 2048
#define F_ 128

// workspace (u64 units)
#define WS_P1 0        // [512]            tagged per-block a_j partial sums
#define WS_SF 512      // [8*128*2]        tagged finals {s0,s1} per (batch,col)
#define WS_P2 2560     // [8*128*2*64]     tagged per-block s-partials, kb contiguous

typedef __attribute__((ext_vector_type(8))) short short8v;
typedef __attribute__((ext_vector_type(4))) float f32x4;
typedef unsigned long long u64;

__device__ inline short f2bf(float f) {
    union { float f; unsigned u; } c; c.f = f;
    unsigned r = (c.u + 0x7FFFu + ((c.u >> 16) & 1u)) >> 16;
    return (short)r;
}
__device__ inline void store_pair(u64* p, float f) {
    union { float f; unsigned u; } c; c.f = f;
    const u64 v = ((u64)(~c.u) << 32) | (u64)c.u;
    __hip_atomic_store(p, v, __ATOMIC_RELAXED, __HIP_MEMORY_SCOPE_AGENT);
}
__device__ inline bool pair_ok(u64 v) {
    return (unsigned)(v >> 32) == (unsigned)(~(unsigned)v);
}
__device__ inline float pair_val(u64 v) {
    union { unsigned u; float f; } c; c.u = (unsigned)v;
    return c.f;
}

__global__ __launch_bounds__(256, 2) void gcn_one(
    const float* __restrict__ x, const float* __restrict__ adj_w,
    const float* __restrict__ adj_b_p, const float* __restrict__ weight,
    const float* __restrict__ bias, float* __restrict__ outx,
    u64* __restrict__ P1, u64* __restrict__ SF, u64* __restrict__ P2)
{
    __shared__ unsigned short wt[128 * 128];   // W^T bf16, slot-swizzled
    __shared__ float adjw[256];
    __shared__ float ail[32], ajl[32];
    __shared__ float disl[32], ajdl[32];
    __shared__ float red0[4][64], red1[4][64];
    __shared__ float s0l[128], s1l[128], bl[128];
    __shared__ float Ash;

    const int bid = blockIdx.x;
    const int b = bid >> 6, kbme = bid & 63, r0 = kbme * 32;
    const int t = threadIdx.x;
    const int lane = t & 63, w = t >> 6;
    const int u = lane & 15, g = lane >> 4;

    adjw[t] = adj_w[t];
    if (t < 128) bl[t] = bias[t];
    __syncthreads();

    // ---- phase 1: per-row a_i, a_j (coalesced x read; x's HBM fetch)
    {
        const int row = t >> 3, kseg = t & 7;
        const float* xp = x + (size_t)(b * N_ + r0 + row) * F_ + kseg * 16;
        float ai = 0.f, aj = 0.f;
        #pragma unroll
        for (int p = 0; p < 4; ++p) {
            const float4 v = *reinterpret_cast<const float4*>(xp + p * 4);
            const float vv[4] = {v.x, v.y, v.z, v.w};
            #pragma unroll
            for (int q = 0; q < 4; ++q) {
                const int k = kseg * 16 + p * 4 + q;
                ai = fmaf(vv[q], adjw[k], ai);
                aj = fmaf(vv[q], adjw[128 + k], aj);
            }
        }
        #pragma unroll
        for (int m = 1; m < 8; m <<= 1) {
            ai += __shfl_xor(ai, m, 64);
            aj += __shfl_xor(aj, m, 64);
        }
        if (kseg == 0) { ail[row] = ai + adj_b_p[0]; ajl[row] = aj; }
    }
    __syncthreads();
    if (t < 32) {
        float s = ajl[t];
        #pragma unroll
        for (int off = 16; off > 0; off >>= 1) s += __shfl_down(s, off, 64);
        if (t == 0) store_pair(&P1[bid], s);
    }

    // ---- stage W^T bf16 (independent of barriers)
    {
        const int c = t & 127, khalf = t >> 7;
        for (int j8 = 0; j8 < 8; ++j8) {
            const int kb = khalf * 8 + j8;
            short8v v;
            #pragma unroll
            for (int i = 0; i < 8; ++i)
                v[i] = f2bf(weight[(kb * 8 + i) * F_ + c]);
            const int slot = kb ^ (c & 15);
            *reinterpret_cast<short8v*>(&wt[c * 128 + slot * 8]) = v;
        }
    }
    __syncthreads();

    // ---- MFMA GEMM (independent of both barriers)
    const int wr = (w & 1) * 16;
    const int ct0 = (w >> 1) * 4;
    f32x4 acc[4];
    #pragma unroll
    for (int i = 0; i < 4; ++i) acc[i] = (f32x4)(0.f);
    {
        const float* xrow = x + (size_t)(b * N_ + r0 + wr + u) * F_;
        #pragma unroll
        for (int kk = 0; kk < 4; ++kk) {
            const float4 xa = *reinterpret_cast<const float4*>(xrow + kk * 32 + g * 8);
            const float4 xb = *reinterpret_cast<const float4*>(xrow + kk * 32 + g * 8 + 4);
            short8v af;
            af[0] = f2bf(xa.x); af[1] = f2bf(xa.y); af[2] = f2bf(xa.z); af[3] = f2bf(xa.w);
            af[4] = f2bf(xb.x); af[5] = f2bf(xb.y); af[6] = f2bf(xb.z); af[7] = f2bf(xb.w);
            const int kb = kk * 4 + g;
            #pragma unroll
            for (int c = 0; c < 4; ++c) {
                const int col = (ct0 + c) * 16 + u;
                const int slot = kb ^ u;   // col&15 == u
                const short8v bfv = *reinterpret_cast<const short8v*>(&wt[col * 128 + slot * 8]);
                acc[c] = __builtin_amdgcn_mfma_f32_16x16x32_bf16(af, bfv, acc[c], 0, 0, 0);
            }
        }
    }

    // ---- barrier A: spin on the 64 tagged P1 partials of this batch
    if (t < 64) {
        u64 v;
        while (true) {
            v = __hip_atomic_load(&P1[b * 64 + t], __ATOMIC_RELAXED, __HIP_MEMORY_SCOPE_AGENT);
            if (pair_ok(v)) break;
            __builtin_amdgcn_s_sleep(2);
        }
        float s = pair_val(v);
        #pragma unroll
        for (int off = 32; off > 0; off >>= 1) s += __shfl_down(s, off, 64);
        if (t == 0) Ash = s;
    }
    __syncthreads();
    if (t < 32) {
        const float deg = fmaxf(2048.f * ail[t] + Ash + 1.f, 1.f);
        const float d = rsqrtf(deg);
        disl[t] = d;
        ajdl[t] = ajl[t] * d;
    }
    __syncthreads();

    // ---- s-partials directly from MFMA accumulators
    // wave w: rows wr..wr+15, cols (ct0+c)*16+u. Reduce rows: 4 in-lane + xor 16,32.
    {
        float p0[4], p1[4];
        #pragma unroll
        for (int c = 0; c < 4; ++c) {
            float s0 = 0.f, s1 = 0.f;
            #pragma unroll
            for (int r = 0; r < 4; ++r) {
                const int row = wr + g * 4 + r;
                s0 = fmaf(disl[row], acc[c][r], s0);
                s1 = fmaf(ajdl[row], acc[c][r], s1);
            }
            s0 += __shfl_xor(s0, 16, 64); s0 += __shfl_xor(s0, 32, 64);
            s1 += __shfl_xor(s1, 16, 64); s1 += __shfl_xor(s1, 32, 64);
            p0[c] = s0; p1[c] = s1;
        }
        if (g == 0) {
            #pragma unroll
            for (int c = 0; c < 4; ++c) {
                red0[w][c * 16 + u] = p0[c];
                red1[w][c * 16 + u] = p1[c];
            }
        }
    }
    __syncthreads();
    // publish P2: thread t -> (vec = t>>7, col = t&127); combine row-half waves
    {
        const int c = t & 127, vec = t >> 7;
        const int cg = c >> 6, cc = c & 63;
        const float v = (vec == 0)
            ? (red0[2 * cg][cc] + red0[2 * cg + 1][cc])
            : (red1[2 * cg][cc] + red1[2 * cg + 1][cc]);
        store_pair(&P2[((size_t)((b * 128 + c) * 2 + vec) << 6) + kbme], v);
    }

    // ---- finalizers: blocks kbme<4 reduce 32 cols x 2 vecs x 64 kb, publish SF
    if (kbme < 4) {
        const int p = t >> 2, klo = (t & 3) * 16;
        const int c = kbme * 32 + (p >> 1), vec = p & 1;
        u64* base = &P2[(size_t)((b * 128 + c) * 2 + vec) << 6];
        u64 vv[16];
        bool ok;
        do {
            ok = true;
            #pragma unroll
            for (int i = 0; i < 16; ++i)
                vv[i] = __hip_atomic_load(&base[klo + i], __ATOMIC_RELAXED, __HIP_MEMORY_SCOPE_AGENT);
            #pragma unroll
            for (int i = 0; i < 16; ++i) ok &= pair_ok(vv[i]);
            if (!ok) __builtin_amdgcn_s_sleep(4);
        } while (!ok);
        float s = 0.f;
        #pragma unroll
        for (int i = 0; i < 16; ++i) s += pair_val(vv[i]);
        s += __shfl_xor(s, 1, 64);
        s += __shfl_xor(s, 2, 64);
        if ((t & 3) == 0)
            store_pair(&SF[(b * 128 + c) * 2 + vec], s);
    }

    // ---- barrier B: spin on finals (2 KB per block)
    {
        const int c = t & 127, vec = t >> 7;
        u64 v;
        while (true) {
            v = __hip_atomic_load(&SF[(b * 128 + c) * 2 + vec], __ATOMIC_RELAXED, __HIP_MEMORY_SCOPE_AGENT);
            if (pair_ok(v)) break;
            __builtin_amdgcn_s_sleep(2);
        }
        if (vec == 0) s0l[c] = pair_val(v); else s1l[c] = pair_val(v);
    }
    __syncthreads();

    // ---- epilogue on MFMA accumulators, single out write
    #pragma unroll
    for (int c = 0; c < 4; ++c) {
        const int col = (ct0 + c) * 16 + u;
        const float sv0 = s0l[col], sv1 = s1l[col], bv = bl[col];
        #pragma unroll
        for (int r = 0; r < 4; ++r) {
            const int row = wr + g * 4 + r;
            const float d = disl[row], ab = ail[row];
            const float o = fmaxf(d * (ab * sv0 + sv1 + d * acc[c][r]) + bv, 0.f);
            outx[(size_t)(b * N_ + r0 + row) * F_ + col] = o;
        }
    }
}

extern "C" void kernel_launch(void* const* d_in, const int* in_sizes, int n_in,
                              void* d_out, int out_size, void* d_ws, size_t ws_size,
                              hipStream_t stream) {
    const float* x      = (const float*)d_in[0];
    const float* adj_w  = (const float*)d_in[1];
    const float* adj_b  = (const float*)d_in[2];
    const float* weight = (const float*)d_in[3];
    const float* bias   = (const float*)d_in[4];
    float* out = (float*)d_out;
    u64* ws = (u64*)d_ws;

    gcn_one<<<512, 256, 0, stream>>>(x, adj_w, adj_b, weight, bias, out,
                                     ws + WS_P1, ws + WS_SF, ws + WS_P2);
}